// Round 1
// baseline (2444.351 us; speedup 1.0000x reference)
//
#include <hip/hip_runtime.h>
#include <math.h>

// Problem constants
constexpr int Cc = 128;          // channels
constexpr int Sd = 64;           // D_SIM
constexpr int Gd = 64;           // G_DIM
constexpr int Dd = 48, Hh = 48, Ww = 48;
constexpr int SP = Dd * Hh * Ww; // 110592 voxels per batch
constexpr int NV = 2 * SP;       // 221184 total voxels
constexpr float EPSV = 1e-5f;

// ---------------------------------------------------------------- prep
// Build transposed weight tables in workspace:
//  wT[c*192 + o]  : o<64 -> theta_w[o][c]; o<128 -> phi_w[o-64][c]; else G_w
//  rWT[g*128 + c] : r_w[c][g]
__global__ void k_prep(const float* __restrict__ th, const float* __restrict__ ph,
                       const float* __restrict__ gw, const float* __restrict__ rw,
                       float* __restrict__ wT, float* __restrict__ rWT) {
    int tid = threadIdx.x;
    for (int i = tid; i < 128 * 192; i += blockDim.x) {
        int c = i / 192, o = i % 192;
        float v = (o < 64)  ? th[o * 128 + c]
                : (o < 128) ? ph[(o - 64) * 128 + c]
                            : gw[(o - 128) * 128 + c];
        wT[i] = v;
    }
    for (int i = tid; i < 64 * 128; i += blockDim.x) {
        int g = i / 128, c = i % 128;
        rWT[i] = rw[c * 64 + g];
    }
}

// ---------------------------------------------------------------- projections
// t,p,g = x @ {theta,phi,G}_w.T + bias.  One block = 64 voxels, 192 threads
// (3 waves; wave w computes projection w, 64 outputs/thread).
__global__ __launch_bounds__(192) void k_proj(
        const float* __restrict__ h, const float* __restrict__ wT,
        const float* __restrict__ tb, const float* __restrict__ pb,
        const float* __restrict__ gb,
        float* __restrict__ tO, float* __restrict__ pO, float* __restrict__ gO) {
    __shared__ float sm[3 * 64 * 68];   // 52.2 KB; x-tile uses first 8192 floats
    int blk = blockIdx.x;               // 3456 = NV/64
    int b = blk / (SP / 64);
    int vsp0 = (blk % (SP / 64)) * 64;
    const float* hb = h + (long)b * Cc * SP;
    int tid = threadIdx.x;
    for (int i = tid; i < Cc * 64; i += 192) {
        int c = i >> 6, v = i & 63;
        sm[i] = hb[(long)c * SP + vsp0 + v];
    }
    __syncthreads();
    int v = tid & 63;
    int proj = __builtin_amdgcn_readfirstlane(tid >> 6);  // wave-uniform 0..2
    const float* bias = (proj == 0) ? tb : (proj == 1) ? pb : gb;
    float acc[64];
#pragma unroll
    for (int j = 0; j < 64; ++j) acc[j] = bias[j];
    const float* wbase = wT + proj * 64;
#pragma unroll 1
    for (int c = 0; c < Cc; ++c) {
        float xv = sm[c * 64 + v];
        const float* wr = wbase + c * 192;   // uniform address -> s_load
#pragma unroll
        for (int j = 0; j < 64; ++j) acc[j] += wr[j] * xv;
    }
    __syncthreads();                          // x-tile dead; reuse LDS for staging
    float* st = sm + proj * (64 * 68) + v * 68;
#pragma unroll
    for (int j = 0; j < 16; ++j)
        *(float4*)(st + 4 * j) = make_float4(acc[4*j], acc[4*j+1], acc[4*j+2], acc[4*j+3]);
    __syncthreads();
    long vox0 = (long)b * SP + vsp0;
    for (int i = tid; i < 3 * 4096; i += 192) {
        int pi = i >> 12, r = i & 4095;
        int vv = r >> 6, o = r & 63;
        float val = sm[pi * (64 * 68) + vv * 68 + o];
        float* outp = (pi == 0) ? tO : (pi == 1) ? pO : gO;
        outp[(vox0 + vv) * 64 + o] = val;
    }
}

// ---------------------------------------------------------------- scores
// f[vox][a] = sum_s t[vox][s] * p[key_a][s] along one axis (48x48x64 GEMM/line).
// axis: 0=D (fixed h,w), 1=H (fixed d,w, diag mask), 2=W (fixed d,h, diag mask)
__global__ __launch_bounds__(256) void k_scores(
        const float* __restrict__ t, const float* __restrict__ p,
        float* __restrict__ f, int axis) {
    __shared__ float tl[48 * 68], pl[48 * 68];
    int blk = blockIdx.x;                    // 4608 = 2*48*48
    int b = blk / 2304, rem = blk % 2304;
    int i = rem / 48, j = rem % 48;
    int stride, vsp0;
    if (axis == 0)      { stride = 2304; vsp0 = i * 48 + j; }
    else if (axis == 1) { stride = 48;   vsp0 = i * 2304 + j; }
    else                { stride = 1;    vsp0 = i * 2304 + j * 48; }
    long vox0 = (long)b * SP + vsp0;
    int tid = threadIdx.x;
    for (int q = tid; q < 48 * 64; q += 256) {
        int r = q >> 6, s = q & 63;
        tl[r * 68 + s] = t[(vox0 + (long)r * stride) * 64 + s];
        pl[r * 68 + s] = p[(vox0 + (long)r * stride) * 64 + s];
    }
    __syncthreads();
    int tx = tid & 15, ty = tid >> 4;        // rows 3*ty.. cols 3*tx..
    float acc[3][3] = {};
    for (int k = 0; k < 64; k += 4) {
        float4 tv[3], pv[3];
#pragma unroll
        for (int u = 0; u < 3; ++u) tv[u] = *(const float4*)&tl[(3 * ty + u) * 68 + k];
#pragma unroll
        for (int u = 0; u < 3; ++u) pv[u] = *(const float4*)&pl[(3 * tx + u) * 68 + k];
#pragma unroll
        for (int u = 0; u < 3; ++u)
#pragma unroll
            for (int w = 0; w < 3; ++w)
                acc[u][w] += tv[u].x * pv[w].x + tv[u].y * pv[w].y +
                             tv[u].z * pv[w].z + tv[u].w * pv[w].w;
    }
    bool mask = (axis != 0);
#pragma unroll
    for (int u = 0; u < 3; ++u) {
        int r = 3 * ty + u;
        long obase = (vox0 + (long)r * stride) * 48;
#pragma unroll
        for (int w = 0; w < 3; ++w) {
            int a = 3 * tx + w;
            float vsc = acc[u][w];
            if (mask && a == r) vsc = -1e30f;
            f[obase + a] = vsc;
        }
    }
}

// ---------------------------------------------------------------- softmax
// In-place softmax over the 144 concatenated scores of each voxel. 1 wave/voxel.
__global__ __launch_bounds__(256) void k_softmax(
        float* __restrict__ fD, float* __restrict__ fH, float* __restrict__ fW) {
    int wv = threadIdx.x >> 6, lane = threadIdx.x & 63;
    long vox = (long)blockIdx.x * 4 + wv;    // grid 55296
    float* b0 = fD + vox * 48;
    float* b1 = fH + vox * 48;
    float* b2 = fW + vox * 48;
    float v0 = (lane < 48) ? b0[lane] : b1[lane - 48];
    float v1 = (lane < 32) ? b1[lane + 16] : b2[lane - 32];
    float v2 = (lane < 16) ? b2[lane + 32] : -1e30f;
    float m = fmaxf(v0, fmaxf(v1, v2));
#pragma unroll
    for (int o = 32; o; o >>= 1) m = fmaxf(m, __shfl_xor(m, o, 64));
    float e0 = __expf(v0 - m);
    float e1 = __expf(v1 - m);
    float e2 = (lane < 16) ? __expf(v2 - m) : 0.f;
    float s = e0 + e1 + e2;
#pragma unroll
    for (int o = 32; o; o >>= 1) s += __shfl_xor(s, o, 64);
    float inv = 1.f / s;
    if (lane < 48) b0[lane] = e0 * inv; else b1[lane - 48] = e0 * inv;
    if (lane < 32) b1[lane + 16] = e1 * inv; else b2[lane - 32] = e1 * inv;
    if (lane < 16) b2[lane + 32] = e2 * inv;
}

// ---------------------------------------------------------------- weighted sum
// y[vox][g] (+)= sum_a w[vox][a] * g[key_a][g] along one axis.
__global__ __launch_bounds__(256) void k_ysum(
        const float* __restrict__ wgt, const float* __restrict__ g,
        float* __restrict__ y, int axis, int accum) {
    __shared__ float wl[48 * 49], gl[48 * 68];
    int blk = blockIdx.x;
    int b = blk / 2304, rem = blk % 2304;
    int i = rem / 48, j = rem % 48;
    int stride, vsp0;
    if (axis == 0)      { stride = 2304; vsp0 = i * 48 + j; }
    else if (axis == 1) { stride = 48;   vsp0 = i * 2304 + j; }
    else                { stride = 1;    vsp0 = i * 2304 + j * 48; }
    long vox0 = (long)b * SP + vsp0;
    int tid = threadIdx.x;
    for (int q = tid; q < 48 * 48; q += 256) {
        int r = q / 48, a = q % 48;
        wl[r * 49 + a] = wgt[(vox0 + (long)r * stride) * 48 + a];
    }
    for (int q = tid; q < 48 * 64; q += 256) {
        int r = q >> 6, s = q & 63;
        gl[r * 68 + s] = g[(vox0 + (long)r * stride) * 64 + s];
    }
    __syncthreads();
    int tx = tid & 15, ty = tid >> 4;        // cols 4*tx, rows 3*ty
    float acc[3][4] = {};
    for (int a = 0; a < 48; ++a) {
        float4 gv = *(const float4*)&gl[a * 68 + tx * 4];
#pragma unroll
        for (int u = 0; u < 3; ++u) {
            float wv = wl[(3 * ty + u) * 49 + a];
            acc[u][0] += wv * gv.x; acc[u][1] += wv * gv.y;
            acc[u][2] += wv * gv.z; acc[u][3] += wv * gv.w;
        }
    }
#pragma unroll
    for (int u = 0; u < 3; ++u) {
        long ob = (vox0 + (long)(3 * ty + u) * stride) * 64 + tx * 4;
        float4 pr = accum ? *(const float4*)&y[ob] : make_float4(0, 0, 0, 0);
        *(float4*)&y[ob] = make_float4(pr.x + acc[u][0], pr.y + acc[u][1],
                                       pr.z + acc[u][2], pr.w + acc[u][3]);
    }
}

// ---------------------------------------------------------------- cross proj
// cross[b][c][vox] = sum_g y[vox][g]*r_w[c][g] + r_b[c]   (channel-major out)
__global__ __launch_bounds__(256) void k_cross(
        const float* __restrict__ y, const float* __restrict__ rWT,
        const float* __restrict__ rb, float* __restrict__ cross) {
    __shared__ float sm[8192];               // y-tile [64][65] then c-major staging
    int blk = blockIdx.x;                    // 3456
    int b = blk / (SP / 64);
    int vsp0 = (blk % (SP / 64)) * 64;
    long vox0 = (long)b * SP + vsp0;
    int tid = threadIdx.x;
    for (int q = tid; q < 64 * 64; q += 256) {
        int v = q >> 6, s = q & 63;
        sm[v * 65 + s] = y[(vox0 + v) * 64 + s];
    }
    __syncthreads();
    int v = tid & 63;
    int og = __builtin_amdgcn_readfirstlane(tid >> 6);   // 0..3, channels og*32..
    float acc[32];
#pragma unroll
    for (int jj = 0; jj < 32; ++jj) acc[jj] = rb[og * 32 + jj];
#pragma unroll 1
    for (int gg = 0; gg < 64; ++gg) {
        float yv = sm[v * 65 + gg];
        const float* wr = rWT + gg * 128 + og * 32;      // uniform -> s_load
#pragma unroll
        for (int jj = 0; jj < 32; ++jj) acc[jj] += wr[jj] * yv;
    }
    __syncthreads();
#pragma unroll
    for (int jj = 0; jj < 32; ++jj) sm[(og * 32 + jj) * 64 + v] = acc[jj];
    __syncthreads();
    for (int q = tid; q < 8192; q += 256) {
        int c = q >> 6, vv = q & 63;
        cross[((long)b * Cc + c) * SP + vsp0 + vv] = sm[q];
    }
}

// ---------------------------------------------------------------- GN stats
// partials over cross: grid 1024 = (b*32+grp)*16 + slice, each 27648 floats
__global__ __launch_bounds__(256) void k_gnpart(
        const float* __restrict__ cross, float* __restrict__ part) {
    int blk = blockIdx.x;
    int slice = blk & 15, bg = blk >> 4;
    long base = (long)bg * 4 * SP + (long)slice * (4 * SP / 16);
    const float4* p4 = (const float4*)(cross + base);
    const int n4 = (4 * SP / 16) / 4;        // 6912
    float s = 0.f, ss = 0.f;
    for (int q = threadIdx.x; q < n4; q += 256) {
        float4 v = p4[q];
        s  += v.x + v.y + v.z + v.w;
        ss += v.x * v.x + v.y * v.y + v.z * v.z + v.w * v.w;
    }
#pragma unroll
    for (int o = 32; o; o >>= 1) { s += __shfl_xor(s, o, 64); ss += __shfl_xor(ss, o, 64); }
    __shared__ float rs[4], rss[4];
    int wv = threadIdx.x >> 6;
    if ((threadIdx.x & 63) == 0) { rs[wv] = s; rss[wv] = ss; }
    __syncthreads();
    if (threadIdx.x == 0) {
        float S = 0.f, SS = 0.f;
        for (int q2 = 0; q2 < 4; ++q2) { S += rs[q2]; SS += rss[q2]; }
        part[blk * 2] = S; part[blk * 2 + 1] = SS;
    }
}

__global__ void k_gnfin(const float* __restrict__ part, float* __restrict__ stats) {
    int i = threadIdx.x;                     // 64 = (b*32+grp)
    if (i < 64) {
        float s = 0.f, ss = 0.f;
        for (int q = 0; q < 16; ++q) { s += part[(i * 16 + q) * 2]; ss += part[(i * 16 + q) * 2 + 1]; }
        float n = 4.f * SP;
        float mu = s / n, var = ss / n - mu * mu;
        stats[i * 2] = mu;
        stats[i * 2 + 1] = rsqrtf(var + EPSV);
    }
}

// h_out = h_in + (cross - mu)*inv*gn_w + gn_b   (elementwise, float4)
__global__ __launch_bounds__(256) void k_gnapply(
        const float* __restrict__ hin, const float* __restrict__ cross,
        const float* __restrict__ stats, const float* __restrict__ gw,
        const float* __restrict__ gb, float* __restrict__ hout) {
    long q = ((long)blockIdx.x * 256 + threadIdx.x) * 4;
    int c = (int)((q / SP) & 127);
    int b = (int)(q / ((long)Cc * SP));
    int bg = b * 32 + (c >> 2);
    float mu = stats[bg * 2], inv = stats[bg * 2 + 1];
    float sc = inv * gw[c], sh = gb[c] - mu * sc;
    float4 cv = *(const float4*)(cross + q);
    float4 hv = *(const float4*)(hin + q);
    float4 o = make_float4(hv.x + cv.x * sc + sh, hv.y + cv.y * sc + sh,
                           hv.z + cv.z * sc + sh, hv.w + cv.w * sc + sh);
    *(float4*)(hout + q) = o;
}

// ---------------------------------------------------------------- BN
__global__ __launch_bounds__(256) void k_bnpart(
        const float* __restrict__ h, float* __restrict__ part) {
    int blk = blockIdx.x;                    // 1024 = (b*128+c)*4 + slice
    int slice = blk & 3, bc = blk >> 2;
    long base = (long)bc * SP + (long)slice * (SP / 4);
    const float4* p4 = (const float4*)(h + base);
    const int n4 = (SP / 4) / 4;             // 6912
    float s = 0.f, ss = 0.f;
    for (int q = threadIdx.x; q < n4; q += 256) {
        float4 v = p4[q];
        s  += v.x + v.y + v.z + v.w;
        ss += v.x * v.x + v.y * v.y + v.z * v.z + v.w * v.w;
    }
#pragma unroll
    for (int o = 32; o; o >>= 1) { s += __shfl_xor(s, o, 64); ss += __shfl_xor(ss, o, 64); }
    __shared__ float rs[4], rss[4];
    int wv = threadIdx.x >> 6;
    if ((threadIdx.x & 63) == 0) { rs[wv] = s; rss[wv] = ss; }
    __syncthreads();
    if (threadIdx.x == 0) {
        float S = 0.f, SS = 0.f;
        for (int q2 = 0; q2 < 4; ++q2) { S += rs[q2]; SS += rss[q2]; }
        part[blk * 2] = S; part[blk * 2 + 1] = SS;
    }
}

__global__ void k_bnfin(const float* __restrict__ part, const float* __restrict__ bw,
                        const float* __restrict__ bb, float* __restrict__ ssout) {
    int c = threadIdx.x;                     // 128
    if (c < 128) {
        float s = 0.f, q = 0.f;
        for (int b2 = 0; b2 < 2; ++b2)
            for (int sl = 0; sl < 4; ++sl) {
                int blk = (b2 * 128 + c) * 4 + sl;
                s += part[blk * 2]; q += part[blk * 2 + 1];
            }
        float n = 2.f * SP;
        float mu = s / n, var = q / n - mu * mu;
        float inv = rsqrtf(var + EPSV);
        float a1 = inv * bw[c];
        ssout[c * 2] = a1;
        ssout[c * 2 + 1] = bb[c] - mu * a1;
    }
}

__global__ __launch_bounds__(256) void k_bnrelu(
        const float* __restrict__ h, const float* __restrict__ ssin,
        float* __restrict__ out) {
    long q = ((long)blockIdx.x * 256 + threadIdx.x) * 4;
    int c = (int)((q / SP) & 127);
    float a1 = ssin[c * 2], a0 = ssin[c * 2 + 1];
    float4 v = *(const float4*)(h + q);
    float4 o = make_float4(fmaxf(v.x * a1 + a0, 0.f), fmaxf(v.y * a1 + a0, 0.f),
                           fmaxf(v.z * a1 + a0, 0.f), fmaxf(v.w * a1 + a0, 0.f));
    *(float4*)(out + q) = o;
}

// ---------------------------------------------------------------- launch
extern "C" void kernel_launch(void* const* d_in, const int* in_sizes, int n_in,
                              void* d_out, int out_size, void* d_ws, size_t ws_size,
                              hipStream_t stream) {
    const float* x   = (const float*)d_in[0];
    const float* thw = (const float*)d_in[1];
    const float* thb = (const float*)d_in[2];
    const float* phw = (const float*)d_in[3];
    const float* phb = (const float*)d_in[4];
    const float* gww = (const float*)d_in[5];
    const float* gwb = (const float*)d_in[6];
    const float* rw  = (const float*)d_in[7];
    const float* rb  = (const float*)d_in[8];
    const float* gnw = (const float*)d_in[9];
    const float* gnb = (const float*)d_in[10];
    const float* bnw = (const float*)d_in[11];
    const float* bnb = (const float*)d_in[12];

    float* ws    = (float*)d_ws;
    float* wT    = ws;                        // 24576
    float* rWT   = ws + 24576;                // 8192
    float* part  = ws + 32768;                // 4096
    float* stats = ws + 36864;                // 128
    float* bnss  = ws + 37120;                // 256
    float* tB    = ws + 65536;                // NV*64
    float* pB    = tB + (long)NV * 64;
    float* gB    = pB + (long)NV * 64;
    float* scB   = gB + (long)NV * 64;        // 3 * NV * 48
    float* fD = scB;
    float* fH = scB + (long)NV * 48;
    float* fW = scB + (long)NV * 48 * 2;
    float* yB     = tB;                       // reuse (t dead after scores)
    float* crossB = scB;                      // reuse (scores dead after ysum)
    float* out = (float*)d_out;

    k_prep<<<1, 256, 0, stream>>>(thw, phw, gww, rw, wT, rWT);

    const float* hin = x;
    for (int layer = 0; layer < 2; ++layer) {
        k_proj<<<NV / 64, 192, 0, stream>>>(hin, wT, thb, phb, gwb, tB, pB, gB);
        for (int ax = 0; ax < 3; ++ax)
            k_scores<<<4608, 256, 0, stream>>>(tB, pB,
                (ax == 0 ? fD : ax == 1 ? fH : fW), ax);
        k_softmax<<<NV / 4, 256, 0, stream>>>(fD, fH, fW);
        for (int ax = 0; ax < 3; ++ax)
            k_ysum<<<4608, 256, 0, stream>>>((ax == 0 ? fD : ax == 1 ? fH : fW),
                gB, yB, ax, ax > 0);
        k_cross<<<NV / 64, 256, 0, stream>>>(yB, rWT, rb, crossB);
        k_gnpart<<<1024, 256, 0, stream>>>(crossB, part);
        k_gnfin<<<1, 64, 0, stream>>>(part, stats);
        k_gnapply<<<(int)(((long)2 * Cc * SP / 4) / 256), 256, 0, stream>>>(
            hin, crossB, stats, gnw + layer * 128, gnb + layer * 128, out);
        hin = out;
    }
    k_bnpart<<<1024, 256, 0, stream>>>(out, part);
    k_bnfin<<<1, 128, 0, stream>>>(part, bnw, bnb, bnss);
    k_bnrelu<<<(int)(((long)2 * Cc * SP / 4) / 256), 256, 0, stream>>>(out, bnss, out);
}

// Round 2
// 1929.092 us; speedup vs baseline: 1.2671x; 1.2671x over previous
//
#include <hip/hip_runtime.h>
#include <math.h>

// Problem constants
constexpr int Cc = 128;          // channels
constexpr int Dd = 48, Hh = 48, Ww = 48;
constexpr int SP = Dd * Hh * Ww; // 110592 voxels per batch
constexpr int NV = 2 * SP;       // 221184 total voxels
constexpr float EPSV = 1e-5f;

typedef __attribute__((ext_vector_type(8))) short short8;
typedef __attribute__((ext_vector_type(4))) float f32x4;

static __device__ __forceinline__ ushort f2bf(float f) {
    uint u = __float_as_uint(f);
    uint r = (u + 0x7fffu + ((u >> 16) & 1u)) >> 16;   // RNE
    return (ushort)r;
}

// ---------------------------------------------------------------- prep
// wtb[o*128+c] bf16: o<64 theta_w[o][c]; o<128 phi_w[o-64][c]; else G_w.
// rWT[g*128+c] fp32: r_w[c][g]
__global__ void k_prep(const float* __restrict__ th, const float* __restrict__ ph,
                       const float* __restrict__ gw, const float* __restrict__ rw,
                       ushort* __restrict__ wtb, float* __restrict__ rWT) {
    int tid = threadIdx.x;
    for (int i = tid; i < 192 * 128; i += 256) {
        int o = i >> 7, c = i & 127;
        float v = (o < 64)  ? th[o * 128 + c]
                : (o < 128) ? ph[(o - 64) * 128 + c]
                            : gw[(o - 128) * 128 + c];
        wtb[i] = f2bf(v);
    }
    for (int i = tid; i < 64 * 128; i += 256) {
        int g = i >> 7, c = i & 127;
        rWT[i] = rw[c * 64 + g];
    }
}

// ---------------------------------------------------------------- projections (MFMA)
// out[v][o] = sum_c x[v][c] * W[o][c] + bias[o], o in [0,192).
// Block: 64 voxels, 4 waves; wave = mt (16-voxel row tile). W in swizzled LDS bf16.
// t,p written bf16 (feed scores); g written fp32 (feeds ysum).
__global__ __launch_bounds__(256) void k_proj(
        const float* __restrict__ h, const ushort* __restrict__ wtb,
        const float* __restrict__ tb, const float* __restrict__ pb,
        const float* __restrict__ gb,
        ushort* __restrict__ tO, ushort* __restrict__ pO, float* __restrict__ gO) {
    __shared__ __align__(16) uint wl[192 * 64];   // 48 KB, [o][c-pairs] swizzled
    int tid = threadIdx.x;
    const uint* wu = (const uint*)wtb;
    for (int i = tid; i < 192 * 64; i += 256) {
        int o = i >> 6, dw = i & 63;
        wl[(o << 6) + ((((dw >> 2) ^ (o & 15)) << 2)) + (dw & 3)] = wu[i];
    }
    int blk = blockIdx.x;                         // 3456
    int b = blk / (SP / 64);
    int vsp0 = (blk % (SP / 64)) * 64;
    const float* hb = h + (size_t)b * Cc * SP;
    int lane = tid & 63, wv = tid >> 6;           // wv = mt
    int m = lane & 15, quad = lane >> 4;
    int vg = vsp0 + wv * 16 + m;
    // A fragments from global (quad-coalesced 64B), cvt to bf16
    short8 afr[4];
#pragma unroll
    for (int ks = 0; ks < 4; ++ks) {
        int c0 = ks * 32 + quad * 8;
        float xv[8];
#pragma unroll
        for (int j = 0; j < 8; ++j) xv[j] = hb[(size_t)(c0 + j) * SP + vg];
        union { short8 v; ushort e[8]; } u;
#pragma unroll
        for (int j = 0; j < 8; ++j) u.e[j] = f2bf(xv[j]);
        afr[ks] = u.v;
    }
    __syncthreads();
    int vox = b * SP + vsp0 + wv * 16 + quad * 4;   // + reg
#pragma unroll 1
    for (int nt = 0; nt < 12; ++nt) {
        int o16 = (nt & 3) * 16 + m;
        float bv = (nt < 4) ? tb[o16] : (nt < 8) ? pb[o16] : gb[o16];
        f32x4 acc = {bv, bv, bv, bv};
        int o = nt * 16 + m;
#pragma unroll
        for (int ks = 0; ks < 4; ++ks) {
            int chunk = ks * 4 + quad;
            short8 bfr = *(const short8*)&wl[(o << 6) + ((chunk ^ (o & 15)) << 2)];
            acc = __builtin_amdgcn_mfma_f32_16x16x32_bf16(afr[ks], bfr, acc, 0, 0, 0);
        }
        if (nt < 8) {
            ushort* ob = (nt < 4) ? tO : pO;
#pragma unroll
            for (int r = 0; r < 4; ++r) ob[(size_t)(vox + r) * 64 + o16] = f2bf(acc[r]);
        } else {
#pragma unroll
            for (int r = 0; r < 4; ++r) gO[(size_t)(vox + r) * 64 + o16] = acc[r];
        }
    }
}

// ---------------------------------------------------------------- scores (MFMA, 3 axes)
// f[vox][a] = sum_s t[vox][s]*p[key_a][s] along one axis; wave = one 48-line.
__global__ __launch_bounds__(256) void k_scores(
        const ushort* __restrict__ t, const ushort* __restrict__ p,
        float* __restrict__ fbase) {
    __shared__ __align__(16) uint sl[4 * 3072];   // 48 KB: per-wave tl(1536)+pl(1536)
    int blk = blockIdx.x;                         // 3456 = 3 axes * 1152
    int axis = blk / 1152, rem = blk % 1152;
    int wv = threadIdx.x >> 6, lane = threadIdx.x & 63;
    int L = rem * 4 + wv;                         // 0..4607
    int b = L / 2304, rr = L % 2304, i = rr / 48, j = rr % 48;
    int stride, vsp0;
    if (axis == 0)      { stride = 2304; vsp0 = i * 48 + j; }
    else if (axis == 1) { stride = 48;   vsp0 = i * 2304 + j; }
    else                { stride = 1;    vsp0 = i * 2304 + j * 48; }
    int vox0 = b * SP + vsp0;
    float* f = fbase + (size_t)axis * NV * 48;
    uint* tl = &sl[wv * 3072];
    uint* pl = tl + 1536;
    const uint* tu = (const uint*)t;
    const uint* pu = (const uint*)p;
#pragma unroll 4
    for (int it = 0; it < 24; ++it) {
        int idx = it * 64 + lane;
        int r = idx >> 5, dw = idx & 31;
        int gaddr = (vox0 + r * stride) * 32 + dw;
        int laddr = (r << 5) + (((dw >> 2) ^ (r & 7)) << 2) + (dw & 3);
        tl[laddr] = tu[gaddr];
        pl[laddr] = pu[gaddr];
    }
    __syncthreads();
    int m = lane & 15, quad = lane >> 4;
    short8 afr[3][2];
#pragma unroll
    for (int mt = 0; mt < 3; ++mt)
#pragma unroll
        for (int ks = 0; ks < 2; ++ks) {
            int r = mt * 16 + m, chunk = ks * 4 + quad;
            afr[mt][ks] = *(const short8*)&tl[(r << 5) + ((chunk ^ (r & 7)) << 2)];
        }
    f32x4 acc[3][3];
#pragma unroll
    for (int mt = 0; mt < 3; ++mt)
#pragma unroll
        for (int nt = 0; nt < 3; ++nt) acc[mt][nt] = (f32x4){0.f, 0.f, 0.f, 0.f};
#pragma unroll
    for (int nt = 0; nt < 3; ++nt)
#pragma unroll
        for (int ks = 0; ks < 2; ++ks) {
            int a = nt * 16 + m, chunk = ks * 4 + quad;
            short8 bfr = *(const short8*)&pl[(a << 5) + ((chunk ^ (a & 7)) << 2)];
#pragma unroll
            for (int mt = 0; mt < 3; ++mt)
                acc[mt][nt] = __builtin_amdgcn_mfma_f32_16x16x32_bf16(
                    afr[mt][ks], bfr, acc[mt][nt], 0, 0, 0);
        }
    bool mask = (axis != 0);
#pragma unroll
    for (int mt = 0; mt < 3; ++mt)
#pragma unroll
        for (int nt = 0; nt < 3; ++nt)
#pragma unroll
            for (int r4 = 0; r4 < 4; ++r4) {
                int r = mt * 16 + quad * 4 + r4;
                int a = nt * 16 + m;
                float v = acc[mt][nt][r4];
                if (mask && a == r) v = -1e30f;
                f[(size_t)(vox0 + r * stride) * 48 + a] = v;
            }
}

// ---------------------------------------------------------------- softmax
__global__ __launch_bounds__(256) void k_softmax(
        float* __restrict__ fD, float* __restrict__ fH, float* __restrict__ fW) {
    int wv = threadIdx.x >> 6, lane = threadIdx.x & 63;
    long vox = (long)blockIdx.x * 4 + wv;    // grid 55296
    float* b0 = fD + vox * 48;
    float* b1 = fH + vox * 48;
    float* b2 = fW + vox * 48;
    float v0 = (lane < 48) ? b0[lane] : b1[lane - 48];
    float v1 = (lane < 32) ? b1[lane + 16] : b2[lane - 32];
    float v2 = (lane < 16) ? b2[lane + 32] : -1e30f;
    float m = fmaxf(v0, fmaxf(v1, v2));
#pragma unroll
    for (int o = 32; o; o >>= 1) m = fmaxf(m, __shfl_xor(m, o, 64));
    float e0 = __expf(v0 - m);
    float e1 = __expf(v1 - m);
    float e2 = (lane < 16) ? __expf(v2 - m) : 0.f;
    float s = e0 + e1 + e2;
#pragma unroll
    for (int o = 32; o; o >>= 1) s += __shfl_xor(s, o, 64);
    float inv = 1.f / s;
    if (lane < 48) b0[lane] = e0 * inv; else b1[lane - 48] = e0 * inv;
    if (lane < 32) b1[lane + 16] = e1 * inv; else b2[lane - 32] = e1 * inv;
    if (lane < 16) b2[lane + 32] = e2 * inv;
}

// ---------------------------------------------------------------- weighted sum
__global__ __launch_bounds__(256) void k_ysum(
        const float* __restrict__ wgt, const float* __restrict__ g,
        float* __restrict__ y, int axis, int accum) {
    __shared__ float wl[48 * 49], gl[48 * 68];
    int blk = blockIdx.x;
    int b = blk / 2304, rem = blk % 2304;
    int i = rem / 48, j = rem % 48;
    int stride, vsp0;
    if (axis == 0)      { stride = 2304; vsp0 = i * 48 + j; }
    else if (axis == 1) { stride = 48;   vsp0 = i * 2304 + j; }
    else                { stride = 1;    vsp0 = i * 2304 + j * 48; }
    long vox0 = (long)b * SP + vsp0;
    int tid = threadIdx.x;
    for (int q = tid; q < 48 * 48; q += 256) {
        int r = q / 48, a = q % 48;
        wl[r * 49 + a] = wgt[(vox0 + (long)r * stride) * 48 + a];
    }
    for (int q = tid; q < 48 * 64; q += 256) {
        int r = q >> 6, s = q & 63;
        gl[r * 68 + s] = g[(vox0 + (long)r * stride) * 64 + s];
    }
    __syncthreads();
    int tx = tid & 15, ty = tid >> 4;
    float acc[3][4] = {};
    for (int a = 0; a < 48; ++a) {
        float4 gv = *(const float4*)&gl[a * 68 + tx * 4];
#pragma unroll
        for (int u = 0; u < 3; ++u) {
            float wv = wl[(3 * ty + u) * 49 + a];
            acc[u][0] += wv * gv.x; acc[u][1] += wv * gv.y;
            acc[u][2] += wv * gv.z; acc[u][3] += wv * gv.w;
        }
    }
#pragma unroll
    for (int u = 0; u < 3; ++u) {
        long ob = (vox0 + (long)(3 * ty + u) * stride) * 64 + tx * 4;
        float4 pr = accum ? *(const float4*)&y[ob] : make_float4(0, 0, 0, 0);
        *(float4*)&y[ob] = make_float4(pr.x + acc[u][0], pr.y + acc[u][1],
                                       pr.z + acc[u][2], pr.w + acc[u][3]);
    }
}

// ---------------------------------------------------------------- cross proj
__global__ __launch_bounds__(256) void k_cross(
        const float* __restrict__ y, const float* __restrict__ rWT,
        const float* __restrict__ rb, float* __restrict__ cross) {
    __shared__ float sm[8192];
    int blk = blockIdx.x;                    // 3456
    int b = blk / (SP / 64);
    int vsp0 = (blk % (SP / 64)) * 64;
    long vox0 = (long)b * SP + vsp0;
    int tid = threadIdx.x;
    for (int q = tid; q < 64 * 64; q += 256) {
        int v = q >> 6, s = q & 63;
        sm[v * 65 + s] = y[(vox0 + v) * 64 + s];
    }
    __syncthreads();
    int v = tid & 63;
    int og = __builtin_amdgcn_readfirstlane(tid >> 6);
    float acc[32];
#pragma unroll
    for (int jj = 0; jj < 32; ++jj) acc[jj] = rb[og * 32 + jj];
#pragma unroll 1
    for (int gg = 0; gg < 64; ++gg) {
        float yv = sm[v * 65 + gg];
        const float* wr = rWT + gg * 128 + og * 32;
#pragma unroll
        for (int jj = 0; jj < 32; ++jj) acc[jj] += wr[jj] * yv;
    }
    __syncthreads();
#pragma unroll
    for (int jj = 0; jj < 32; ++jj) sm[(og * 32 + jj) * 64 + v] = acc[jj];
    __syncthreads();
    for (int q = tid; q < 8192; q += 256) {
        int c = q >> 6, vv = q & 63;
        cross[((long)b * Cc + c) * SP + vsp0 + vv] = sm[q];
    }
}

// ---------------------------------------------------------------- GN stats
__global__ __launch_bounds__(256) void k_gnpart(
        const float* __restrict__ cross, float* __restrict__ part) {
    int blk = blockIdx.x;                    // 1024
    int slice = blk & 15, bg = blk >> 4;
    long base = (long)bg * 4 * SP + (long)slice * (4 * SP / 16);
    const float4* p4 = (const float4*)(cross + base);
    const int n4 = (4 * SP / 16) / 4;
    float s = 0.f, ss = 0.f;
    for (int q = threadIdx.x; q < n4; q += 256) {
        float4 v = p4[q];
        s  += v.x + v.y + v.z + v.w;
        ss += v.x * v.x + v.y * v.y + v.z * v.z + v.w * v.w;
    }
#pragma unroll
    for (int o = 32; o; o >>= 1) { s += __shfl_xor(s, o, 64); ss += __shfl_xor(ss, o, 64); }
    __shared__ float rs[4], rss[4];
    int wv = threadIdx.x >> 6;
    if ((threadIdx.x & 63) == 0) { rs[wv] = s; rss[wv] = ss; }
    __syncthreads();
    if (threadIdx.x == 0) {
        float S = 0.f, SS = 0.f;
        for (int q2 = 0; q2 < 4; ++q2) { S += rs[q2]; SS += rss[q2]; }
        part[blk * 2] = S; part[blk * 2 + 1] = SS;
    }
}

__global__ void k_gnfin(const float* __restrict__ part, float* __restrict__ stats) {
    int i = threadIdx.x;
    if (i < 64) {
        float s = 0.f, ss = 0.f;
        for (int q = 0; q < 16; ++q) { s += part[(i * 16 + q) * 2]; ss += part[(i * 16 + q) * 2 + 1]; }
        float n = 4.f * SP;
        float mu = s / n, var = ss / n - mu * mu;
        stats[i * 2] = mu;
        stats[i * 2 + 1] = rsqrtf(var + EPSV);
    }
}

__global__ __launch_bounds__(256) void k_gnapply(
        const float* __restrict__ hin, const float* __restrict__ cross,
        const float* __restrict__ stats, const float* __restrict__ gw,
        const float* __restrict__ gb, float* __restrict__ hout) {
    long q = ((long)blockIdx.x * 256 + threadIdx.x) * 4;
    int c = (int)((q / SP) & 127);
    int b = (int)(q / ((long)Cc * SP));
    int bg = b * 32 + (c >> 2);
    float mu = stats[bg * 2], inv = stats[bg * 2 + 1];
    float sc = inv * gw[c], sh = gb[c] - mu * sc;
    float4 cv = *(const float4*)(cross + q);
    float4 hv = *(const float4*)(hin + q);
    float4 o = make_float4(hv.x + cv.x * sc + sh, hv.y + cv.y * sc + sh,
                           hv.z + cv.z * sc + sh, hv.w + cv.w * sc + sh);
    *(float4*)(hout + q) = o;
}

// ---------------------------------------------------------------- BN
__global__ __launch_bounds__(256) void k_bnpart(
        const float* __restrict__ h, float* __restrict__ part) {
    int blk = blockIdx.x;                    // 1024
    int slice = blk & 3, bc = blk >> 2;
    long base = (long)bc * SP + (long)slice * (SP / 4);
    const float4* p4 = (const float4*)(h + base);
    const int n4 = (SP / 4) / 4;
    float s = 0.f, ss = 0.f;
    for (int q = threadIdx.x; q < n4; q += 256) {
        float4 v = p4[q];
        s  += v.x + v.y + v.z + v.w;
        ss += v.x * v.x + v.y * v.y + v.z * v.z + v.w * v.w;
    }
#pragma unroll
    for (int o = 32; o; o >>= 1) { s += __shfl_xor(s, o, 64); ss += __shfl_xor(ss, o, 64); }
    __shared__ float rs[4], rss[4];
    int wv = threadIdx.x >> 6;
    if ((threadIdx.x & 63) == 0) { rs[wv] = s; rss[wv] = ss; }
    __syncthreads();
    if (threadIdx.x == 0) {
        float S = 0.f, SS = 0.f;
        for (int q2 = 0; q2 < 4; ++q2) { S += rs[q2]; SS += rss[q2]; }
        part[blk * 2] = S; part[blk * 2 + 1] = SS;
    }
}

__global__ void k_bnfin(const float* __restrict__ part, const float* __restrict__ bw,
                        const float* __restrict__ bb, float* __restrict__ ssout) {
    int c = threadIdx.x;
    if (c < 128) {
        float s = 0.f, q = 0.f;
        for (int b2 = 0; b2 < 2; ++b2)
            for (int sl = 0; sl < 4; ++sl) {
                int blk = (b2 * 128 + c) * 4 + sl;
                s += part[blk * 2]; q += part[blk * 2 + 1];
            }
        float n = 2.f * SP;
        float mu = s / n, var = q / n - mu * mu;
        float inv = rsqrtf(var + EPSV);
        float a1 = inv * bw[c];
        ssout[c * 2] = a1;
        ssout[c * 2 + 1] = bb[c] - mu * a1;
    }
}

__global__ __launch_bounds__(256) void k_bnrelu(
        const float* __restrict__ h, const float* __restrict__ ssin,
        float* __restrict__ out) {
    long q = ((long)blockIdx.x * 256 + threadIdx.x) * 4;
    int c = (int)((q / SP) & 127);
    float a1 = ssin[c * 2], a0 = ssin[c * 2 + 1];
    float4 v = *(const float4*)(h + q);
    float4 o = make_float4(fmaxf(v.x * a1 + a0, 0.f), fmaxf(v.y * a1 + a0, 0.f),
                           fmaxf(v.z * a1 + a0, 0.f), fmaxf(v.w * a1 + a0, 0.f));
    *(float4*)(out + q) = o;
}

// ---------------------------------------------------------------- launch
extern "C" void kernel_launch(void* const* d_in, const int* in_sizes, int n_in,
                              void* d_out, int out_size, void* d_ws, size_t ws_size,
                              hipStream_t stream) {
    const float* x   = (const float*)d_in[0];
    const float* thw = (const float*)d_in[1];
    const float* thb = (const float*)d_in[2];
    const float* phw = (const float*)d_in[3];
    const float* phb = (const float*)d_in[4];
    const float* gww = (const float*)d_in[5];
    const float* gwb = (const float*)d_in[6];
    const float* rw  = (const float*)d_in[7];
    const float* rb  = (const float*)d_in[8];
    const float* gnw = (const float*)d_in[9];
    const float* gnb = (const float*)d_in[10];
    const float* bnw = (const float*)d_in[11];
    const float* bnb = (const float*)d_in[12];

    float* ws    = (float*)d_ws;
    float* rWT   = ws;                        // 8192 floats
    float* part  = ws + 8192;                 // 2048
    float* stats = ws + 10240;                // 128
    float* bnss  = ws + 10368;                // 256
    ushort* wTb  = (ushort*)(ws + 16384);     // 24576 bf16 = 12288 floats
    ushort* tB16 = (ushort*)(ws + 32768);     // NV*64 bf16 = 7077888 floats
    ushort* pB16 = tB16 + (size_t)NV * 64;
    float* gB    = ws + 32768 + 2 * 7077888;  // NV*64 fp32
    float* yB    = gB + (size_t)NV * 64;      // NV*64 fp32
    float* fbase = yB + (size_t)NV * 64;      // 3*NV*48 fp32
    float* fD = fbase;
    float* fH = fbase + (size_t)NV * 48;
    float* fW = fbase + (size_t)NV * 48 * 2;
    float* crossB = fbase;                    // reuse (scores dead after ysum)
    float* out = (float*)d_out;

    k_prep<<<1, 256, 0, stream>>>(thw, phw, gww, rw, wTb, rWT);

    const float* hin = x;
    for (int layer = 0; layer < 2; ++layer) {
        k_proj<<<NV / 64, 256, 0, stream>>>(hin, wTb, thb, phb, gwb, tB16, pB16, gB);
        k_scores<<<3456, 256, 0, stream>>>(tB16, pB16, fbase);
        k_softmax<<<NV / 4, 256, 0, stream>>>(fD, fH, fW);
        for (int ax = 0; ax < 3; ++ax)
            k_ysum<<<4608, 256, 0, stream>>>((ax == 0 ? fD : ax == 1 ? fH : fW),
                gB, yB, ax, ax > 0);
        k_cross<<<NV / 64, 256, 0, stream>>>(yB, rWT, rb, crossB);
        k_gnpart<<<1024, 256, 0, stream>>>(crossB, part);
        k_gnfin<<<1, 64, 0, stream>>>(part, stats);
        k_gnapply<<<(int)(((long)2 * Cc * SP / 4) / 256), 256, 0, stream>>>(
            hin, crossB, stats, gnw + layer * 128, gnb + layer * 128, out);
        hin = out;
    }
    k_bnpart<<<1024, 256, 0, stream>>>(out, part);
    k_bnfin<<<1, 128, 0, stream>>>(part, bnw, bnb, bnss);
    k_bnrelu<<<(int)(((long)2 * Cc * SP / 4) / 256), 256, 0, stream>>>(out, bnss, out);
}

// Round 3
// 1272.722 us; speedup vs baseline: 1.9206x; 1.5157x over previous
//
#include <hip/hip_runtime.h>
#include <math.h>

// Problem constants
constexpr int Cc = 128;          // channels
constexpr int Dd = 48, Hh = 48, Ww = 48;
constexpr int SP = Dd * Hh * Ww; // 110592 voxels per batch
constexpr int NV = 2 * SP;       // 221184 total voxels
constexpr float EPSV = 1e-5f;

typedef __attribute__((ext_vector_type(8))) short short8;
typedef __attribute__((ext_vector_type(4))) float f32x4;

static __device__ __forceinline__ ushort f2bf(float f) {
    uint u = __float_as_uint(f);
    uint r = (u + 0x7fffu + ((u >> 16) & 1u)) >> 16;   // RNE
    return (ushort)r;
}

// ---------------------------------------------------------------- prep
__global__ void k_prep(const float* __restrict__ th, const float* __restrict__ ph,
                       const float* __restrict__ gw, const float* __restrict__ rw,
                       ushort* __restrict__ wtb, float* __restrict__ rWT) {
    int tid = threadIdx.x;
    for (int i = tid; i < 192 * 128; i += 256) {
        int o = i >> 7, c = i & 127;
        float v = (o < 64)  ? th[o * 128 + c]
                : (o < 128) ? ph[(o - 64) * 128 + c]
                            : gw[(o - 128) * 128 + c];
        wtb[i] = f2bf(v);
    }
    for (int i = tid; i < 64 * 128; i += 256) {
        int g = i >> 7, c = i & 127;
        rWT[i] = rw[c * 64 + g];
    }
}

// ---------------------------------------------------------------- projections (MFMA)
// t,p,g written bf16.
__global__ __launch_bounds__(256) void k_proj(
        const float* __restrict__ h, const ushort* __restrict__ wtb,
        const float* __restrict__ tb, const float* __restrict__ pb,
        const float* __restrict__ gb,
        ushort* __restrict__ tO, ushort* __restrict__ pO, ushort* __restrict__ gO) {
    __shared__ __align__(16) uint wl[192 * 64];   // 48 KB, [o][c-pairs] swizzled
    int tid = threadIdx.x;
    const uint* wu = (const uint*)wtb;
    for (int i = tid; i < 192 * 64; i += 256) {
        int o = i >> 6, dw = i & 63;
        wl[(o << 6) + ((((dw >> 2) ^ (o & 15)) << 2)) + (dw & 3)] = wu[i];
    }
    int blk = blockIdx.x;                         // 3456
    int b = blk / (SP / 64);
    int vsp0 = (blk % (SP / 64)) * 64;
    const float* hb = h + (size_t)b * Cc * SP;
    int lane = tid & 63, wv = tid >> 6;
    int m = lane & 15, quad = lane >> 4;
    int vg = vsp0 + wv * 16 + m;
    short8 afr[4];
#pragma unroll
    for (int ks = 0; ks < 4; ++ks) {
        int c0 = ks * 32 + quad * 8;
        float xv[8];
#pragma unroll
        for (int j = 0; j < 8; ++j) xv[j] = hb[(size_t)(c0 + j) * SP + vg];
        union { short8 v; ushort e[8]; } u;
#pragma unroll
        for (int j = 0; j < 8; ++j) u.e[j] = f2bf(xv[j]);
        afr[ks] = u.v;
    }
    __syncthreads();
    int vox = b * SP + vsp0 + wv * 16 + quad * 4;
#pragma unroll 1
    for (int nt = 0; nt < 12; ++nt) {
        int o16 = (nt & 3) * 16 + m;
        float bv = (nt < 4) ? tb[o16] : (nt < 8) ? pb[o16] : gb[o16];
        f32x4 acc = {bv, bv, bv, bv};
        int o = nt * 16 + m;
#pragma unroll
        for (int ks = 0; ks < 4; ++ks) {
            int chunk = ks * 4 + quad;
            short8 bfr = *(const short8*)&wl[(o << 6) + ((chunk ^ (o & 15)) << 2)];
            acc = __builtin_amdgcn_mfma_f32_16x16x32_bf16(afr[ks], bfr, acc, 0, 0, 0);
        }
        ushort* ob = (nt < 4) ? tO : (nt < 8) ? pO : gO;
#pragma unroll
        for (int r = 0; r < 4; ++r) ob[(size_t)(vox + r) * 64 + o16] = f2bf(acc[r]);
    }
}

// ---------------------------------------------------------------- scores (MFMA, 3 axes)
__global__ __launch_bounds__(256) void k_scores(
        const ushort* __restrict__ t, const ushort* __restrict__ p,
        float* __restrict__ fbase) {
    __shared__ __align__(16) uint sl[4 * 3072];
    int blk = blockIdx.x;                         // 3456 = 3 axes * 1152
    int axis = blk / 1152, rem = blk % 1152;
    int wv = threadIdx.x >> 6, lane = threadIdx.x & 63;
    int L = rem * 4 + wv;
    int b = L / 2304, rr = L % 2304, i = rr / 48, j = rr % 48;
    int stride, vsp0;
    if (axis == 0)      { stride = 2304; vsp0 = i * 48 + j; }
    else if (axis == 1) { stride = 48;   vsp0 = i * 2304 + j; }
    else                { stride = 1;    vsp0 = i * 2304 + j * 48; }
    int vox0 = b * SP + vsp0;
    float* f = fbase + (size_t)axis * NV * 48;
    uint* tl = &sl[wv * 3072];
    uint* pl = tl + 1536;
    const uint* tu = (const uint*)t;
    const uint* pu = (const uint*)p;
#pragma unroll 4
    for (int it = 0; it < 24; ++it) {
        int idx = it * 64 + lane;
        int r = idx >> 5, dw = idx & 31;
        int gaddr = (vox0 + r * stride) * 32 + dw;
        int laddr = (r << 5) + (((dw >> 2) ^ (r & 7)) << 2) + (dw & 3);
        tl[laddr] = tu[gaddr];
        pl[laddr] = pu[gaddr];
    }
    __syncthreads();
    int m = lane & 15, quad = lane >> 4;
    short8 afr[3][2];
#pragma unroll
    for (int mt = 0; mt < 3; ++mt)
#pragma unroll
        for (int ks = 0; ks < 2; ++ks) {
            int r = mt * 16 + m, chunk = ks * 4 + quad;
            afr[mt][ks] = *(const short8*)&tl[(r << 5) + ((chunk ^ (r & 7)) << 2)];
        }
    f32x4 acc[3][3];
#pragma unroll
    for (int mt = 0; mt < 3; ++mt)
#pragma unroll
        for (int nt = 0; nt < 3; ++nt) acc[mt][nt] = (f32x4){0.f, 0.f, 0.f, 0.f};
#pragma unroll
    for (int nt = 0; nt < 3; ++nt)
#pragma unroll
        for (int ks = 0; ks < 2; ++ks) {
            int a = nt * 16 + m, chunk = ks * 4 + quad;
            short8 bfr = *(const short8*)&pl[(a << 5) + ((chunk ^ (a & 7)) << 2)];
#pragma unroll
            for (int mt = 0; mt < 3; ++mt)
                acc[mt][nt] = __builtin_amdgcn_mfma_f32_16x16x32_bf16(
                    afr[mt][ks], bfr, acc[mt][nt], 0, 0, 0);
        }
    bool mask = (axis != 0);
#pragma unroll
    for (int mt = 0; mt < 3; ++mt)
#pragma unroll
        for (int nt = 0; nt < 3; ++nt)
#pragma unroll
            for (int r4 = 0; r4 < 4; ++r4) {
                int r = mt * 16 + quad * 4 + r4;
                int a = nt * 16 + m;
                float v = acc[mt][nt][r4];
                if (mask && a == r) v = -1e30f;
                f[(size_t)(vox0 + r * stride) * 48 + a] = v;
            }
}

// ---------------------------------------------------------------- softmax (in-place fp32)
__global__ __launch_bounds__(256) void k_softmax(
        float* __restrict__ fD, float* __restrict__ fH, float* __restrict__ fW) {
    int wv = threadIdx.x >> 6, lane = threadIdx.x & 63;
    long vox = (long)blockIdx.x * 4 + wv;
    float* b0 = fD + vox * 48;
    float* b1 = fH + vox * 48;
    float* b2 = fW + vox * 48;
    float v0 = (lane < 48) ? b0[lane] : b1[lane - 48];
    float v1 = (lane < 32) ? b1[lane + 16] : b2[lane - 32];
    float v2 = (lane < 16) ? b2[lane + 32] : -1e30f;
    float m = fmaxf(v0, fmaxf(v1, v2));
#pragma unroll
    for (int o = 32; o; o >>= 1) m = fmaxf(m, __shfl_xor(m, o, 64));
    float e0 = __expf(v0 - m);
    float e1 = __expf(v1 - m);
    float e2 = (lane < 16) ? __expf(v2 - m) : 0.f;
    float s = e0 + e1 + e2;
#pragma unroll
    for (int o = 32; o; o >>= 1) s += __shfl_xor(s, o, 64);
    float inv = 1.f / s;
    if (lane < 48) b0[lane] = e0 * inv; else b1[lane - 48] = e0 * inv;
    if (lane < 32) b1[lane + 16] = e1 * inv; else b2[lane - 32] = e1 * inv;
    if (lane < 16) b2[lane + 32] = e2 * inv;
}

// ---------------------------------------------------------------- weighted sum (MFMA)
// Y[48x64] (+)= W[48x48] . G[48x64] per line; 1 wave/line, 2 waves/block.
// W: fp32 softmax weights -> bf16 swizzled LDS (zero-pad k 48..63).
// G: bf16 [vox][64] -> transposed in-register (shfl_xor 32) -> [s][a] swizzled LDS.
__global__ __launch_bounds__(128) void k_ysum(
        const float* __restrict__ wgt, const ushort* __restrict__ g,
        float* __restrict__ y, int axis, int accum) {
    __shared__ __align__(16) uint sl[2 * 3584];   // per-wave wl 1536 + gl 2048 dw
    int wv = threadIdx.x >> 6, lane = threadIdx.x & 63;
    uint* wl = &sl[wv * 3584];
    uint* gl = wl + 1536;
    int L = blockIdx.x * 2 + wv;                  // 0..4607
    int b = L / 2304, rr = L % 2304, i = rr / 48, j = rr % 48;
    int stride, vsp0;
    if (axis == 0)      { stride = 2304; vsp0 = i * 48 + j; }
    else if (axis == 1) { stride = 48;   vsp0 = i * 2304 + j; }
    else                { stride = 1;    vsp0 = i * 2304 + j * 48; }
    int vox0 = b * SP + vsp0;
    // W staging: fp32 -> bf16 pairs, swizzled; dw>=24 zero (K-pad)
#pragma unroll 4
    for (int it = 0; it < 24; ++it) {
        int idx = it * 64 + lane;
        int r = idx >> 5, dw = idx & 31;
        uint pk = 0;
        if (dw < 24) {
            const float* src = wgt + (size_t)(vox0 + r * stride) * 48 + dw * 2;
            pk = (uint)f2bf(src[0]) | ((uint)f2bf(src[1]) << 16);
        }
        wl[(r << 5) + (((dw >> 2) ^ (r & 7)) << 2) + (dw & 3)] = pk;
    }
    // gl zero-pad chunks 6,7 (a>=48): avoid 0 x stale-NaN = NaN
#pragma unroll
    for (int it = 0; it < 8; ++it) {
        int idx = it * 64 + lane;
        int s = idx >> 3, dwp = 24 + (idx & 7);
        gl[(s << 5) + ((((dwp >> 2)) ^ (s & 7)) << 2) + (dwp & 3)] = 0;
    }
    // G transpose staging: read [a][s-pairs] dwords, shfl-pair a/a^1, write [s][a-pairs]
    const uint* gu = (const uint*)g;
#pragma unroll 4
    for (int it = 0; it < 24; ++it) {
        int a = it * 2 + (lane >> 5);
        int dw = lane & 31;
        uint v = gu[(size_t)(vox0 + a * stride) * 32 + dw];
        uint w = (uint)__shfl_xor((int)v, 32, 64);
        uint dst; int s;
        if (lane < 32) { s = dw * 2;     dst = (v & 0xffffu) | (w << 16); }
        else           { s = dw * 2 + 1; dst = (w >> 16) | (v & 0xffff0000u); }
        int adw = it;
        gl[(s << 5) + ((((adw >> 2)) ^ (s & 7)) << 2) + (adw & 3)] = dst;
    }
    // per-wave LDS slice: no __syncthreads needed (in-wave DS ordering)
    int m = lane & 15, quad = lane >> 4;
    short8 afr[3][2];
#pragma unroll
    for (int mt = 0; mt < 3; ++mt)
#pragma unroll
        for (int ks = 0; ks < 2; ++ks) {
            int r = mt * 16 + m, chunk = ks * 4 + quad;
            afr[mt][ks] = *(const short8*)&wl[(r << 5) + ((chunk ^ (r & 7)) << 2)];
        }
    f32x4 acc[3][4];
#pragma unroll
    for (int mt = 0; mt < 3; ++mt)
#pragma unroll
        for (int nt = 0; nt < 4; ++nt) acc[mt][nt] = (f32x4){0.f, 0.f, 0.f, 0.f};
#pragma unroll
    for (int nt = 0; nt < 4; ++nt)
#pragma unroll
        for (int ks = 0; ks < 2; ++ks) {
            int s = nt * 16 + m, chunk = ks * 4 + quad;
            short8 bfr = *(const short8*)&gl[(s << 5) + ((chunk ^ (s & 7)) << 2)];
#pragma unroll
            for (int mt = 0; mt < 3; ++mt)
                acc[mt][nt] = __builtin_amdgcn_mfma_f32_16x16x32_bf16(
                    afr[mt][ks], bfr, acc[mt][nt], 0, 0, 0);
        }
#pragma unroll
    for (int mt = 0; mt < 3; ++mt)
#pragma unroll
        for (int nt = 0; nt < 4; ++nt)
#pragma unroll
            for (int r4 = 0; r4 < 4; ++r4) {
                int r = mt * 16 + quad * 4 + r4;
                size_t addr = (size_t)(vox0 + r * stride) * 64 + nt * 16 + m;
                float pr = accum ? y[addr] : 0.f;
                y[addr] = pr + acc[mt][nt][r4];
            }
}

// ---------------------------------------------------------------- cross proj
__global__ __launch_bounds__(256) void k_cross(
        const float* __restrict__ y, const float* __restrict__ rWT,
        const float* __restrict__ rb, float* __restrict__ cross) {
    __shared__ float sm[8192];
    int blk = blockIdx.x;                    // 3456
    int b = blk / (SP / 64);
    int vsp0 = (blk % (SP / 64)) * 64;
    long vox0 = (long)b * SP + vsp0;
    int tid = threadIdx.x;
    for (int q = tid; q < 64 * 64; q += 256) {
        int v = q >> 6, s = q & 63;
        sm[v * 65 + s] = y[(vox0 + v) * 64 + s];
    }
    __syncthreads();
    int v = tid & 63;
    int og = __builtin_amdgcn_readfirstlane(tid >> 6);
    float acc[32];
#pragma unroll
    for (int jj = 0; jj < 32; ++jj) acc[jj] = rb[og * 32 + jj];
#pragma unroll 1
    for (int gg = 0; gg < 64; ++gg) {
        float yv = sm[v * 65 + gg];
        const float* wr = rWT + gg * 128 + og * 32;
#pragma unroll
        for (int jj = 0; jj < 32; ++jj) acc[jj] += wr[jj] * yv;
    }
    __syncthreads();
#pragma unroll
    for (int jj = 0; jj < 32; ++jj) sm[(og * 32 + jj) * 64 + v] = acc[jj];
    __syncthreads();
    for (int q = tid; q < 8192; q += 256) {
        int c = q >> 6, vv = q & 63;
        cross[((long)b * Cc + c) * SP + vsp0 + vv] = sm[q];
    }
}

// ---------------------------------------------------------------- GN stats
__global__ __launch_bounds__(256) void k_gnpart(
        const float* __restrict__ cross, float* __restrict__ part) {
    int blk = blockIdx.x;                    // 1024
    int slice = blk & 15, bg = blk >> 4;
    long base = (long)bg * 4 * SP + (long)slice * (4 * SP / 16);
    const float4* p4 = (const float4*)(cross + base);
    const int n4 = (4 * SP / 16) / 4;
    float s = 0.f, ss = 0.f;
    for (int q = threadIdx.x; q < n4; q += 256) {
        float4 v = p4[q];
        s  += v.x + v.y + v.z + v.w;
        ss += v.x * v.x + v.y * v.y + v.z * v.z + v.w * v.w;
    }
#pragma unroll
    for (int o = 32; o; o >>= 1) { s += __shfl_xor(s, o, 64); ss += __shfl_xor(ss, o, 64); }
    __shared__ float rs[4], rss[4];
    int wv = threadIdx.x >> 6;
    if ((threadIdx.x & 63) == 0) { rs[wv] = s; rss[wv] = ss; }
    __syncthreads();
    if (threadIdx.x == 0) {
        float S = 0.f, SS = 0.f;
        for (int q2 = 0; q2 < 4; ++q2) { S += rs[q2]; SS += rss[q2]; }
        part[blk * 2] = S; part[blk * 2 + 1] = SS;
    }
}

__global__ void k_gnfin(const float* __restrict__ part, float* __restrict__ stats) {
    int i = threadIdx.x;
    if (i < 64) {
        float s = 0.f, ss = 0.f;
        for (int q = 0; q < 16; ++q) { s += part[(i * 16 + q) * 2]; ss += part[(i * 16 + q) * 2 + 1]; }
        float n = 4.f * SP;
        float mu = s / n, var = ss / n - mu * mu;
        stats[i * 2] = mu;
        stats[i * 2 + 1] = rsqrtf(var + EPSV);
    }
}

__global__ __launch_bounds__(256) void k_gnapply(
        const float* __restrict__ hin, const float* __restrict__ cross,
        const float* __restrict__ stats, const float* __restrict__ gw,
        const float* __restrict__ gb, float* __restrict__ hout) {
    long q = ((long)blockIdx.x * 256 + threadIdx.x) * 4;
    int c = (int)((q / SP) & 127);
    int b = (int)(q / ((long)Cc * SP));
    int bg = b * 32 + (c >> 2);
    float mu = stats[bg * 2], inv = stats[bg * 2 + 1];
    float sc = inv * gw[c], sh = gb[c] - mu * sc;
    float4 cv = *(const float4*)(cross + q);
    float4 hv = *(const float4*)(hin + q);
    float4 o = make_float4(hv.x + cv.x * sc + sh, hv.y + cv.y * sc + sh,
                           hv.z + cv.z * sc + sh, hv.w + cv.w * sc + sh);
    *(float4*)(hout + q) = o;
}

// ---------------------------------------------------------------- BN
__global__ __launch_bounds__(256) void k_bnpart(
        const float* __restrict__ h, float* __restrict__ part) {
    int blk = blockIdx.x;                    // 1024
    int slice = blk & 3, bc = blk >> 2;
    long base = (long)bc * SP + (long)slice * (SP / 4);
    const float4* p4 = (const float4*)(h + base);
    const int n4 = (SP / 4) / 4;
    float s = 0.f, ss = 0.f;
    for (int q = threadIdx.x; q < n4; q += 256) {
        float4 v = p4[q];
        s  += v.x + v.y + v.z + v.w;
        ss += v.x * v.x + v.y * v.y + v.z * v.z + v.w * v.w;
    }
#pragma unroll
    for (int o = 32; o; o >>= 1) { s += __shfl_xor(s, o, 64); ss += __shfl_xor(ss, o, 64); }
    __shared__ float rs[4], rss[4];
    int wv = threadIdx.x >> 6;
    if ((threadIdx.x & 63) == 0) { rs[wv] = s; rss[wv] = ss; }
    __syncthreads();
    if (threadIdx.x == 0) {
        float S = 0.f, SS = 0.f;
        for (int q2 = 0; q2 < 4; ++q2) { S += rs[q2]; SS += rss[q2]; }
        part[blk * 2] = S; part[blk * 2 + 1] = SS;
    }
}

__global__ void k_bnfin(const float* __restrict__ part, const float* __restrict__ bw,
                        const float* __restrict__ bb, float* __restrict__ ssout) {
    int c = threadIdx.x;
    if (c < 128) {
        float s = 0.f, q = 0.f;
        for (int b2 = 0; b2 < 2; ++b2)
            for (int sl = 0; sl < 4; ++sl) {
                int blk = (b2 * 128 + c) * 4 + sl;
                s += part[blk * 2]; q += part[blk * 2 + 1];
            }
        float n = 2.f * SP;
        float mu = s / n, var = q / n - mu * mu;
        float inv = rsqrtf(var + EPSV);
        float a1 = inv * bw[c];
        ssout[c * 2] = a1;
        ssout[c * 2 + 1] = bb[c] - mu * a1;
    }
}

__global__ __launch_bounds__(256) void k_bnrelu(
        const float* __restrict__ h, const float* __restrict__ ssin,
        float* __restrict__ out) {
    long q = ((long)blockIdx.x * 256 + threadIdx.x) * 4;
    int c = (int)((q / SP) & 127);
    float a1 = ssin[c * 2], a0 = ssin[c * 2 + 1];
    float4 v = *(const float4*)(h + q);
    float4 o = make_float4(fmaxf(v.x * a1 + a0, 0.f), fmaxf(v.y * a1 + a0, 0.f),
                           fmaxf(v.z * a1 + a0, 0.f), fmaxf(v.w * a1 + a0, 0.f));
    *(float4*)(out + q) = o;
}

// ---------------------------------------------------------------- launch
extern "C" void kernel_launch(void* const* d_in, const int* in_sizes, int n_in,
                              void* d_out, int out_size, void* d_ws, size_t ws_size,
                              hipStream_t stream) {
    const float* x   = (const float*)d_in[0];
    const float* thw = (const float*)d_in[1];
    const float* thb = (const float*)d_in[2];
    const float* phw = (const float*)d_in[3];
    const float* phb = (const float*)d_in[4];
    const float* gww = (const float*)d_in[5];
    const float* gwb = (const float*)d_in[6];
    const float* rw  = (const float*)d_in[7];
    const float* rb  = (const float*)d_in[8];
    const float* gnw = (const float*)d_in[9];
    const float* gnb = (const float*)d_in[10];
    const float* bnw = (const float*)d_in[11];
    const float* bnb = (const float*)d_in[12];

    float* ws    = (float*)d_ws;
    float* rWT   = ws;                        // 8192 floats
    float* part  = ws + 8192;                 // 2048
    float* stats = ws + 10240;                // 128
    float* bnss  = ws + 10368;                // 256
    ushort* wTb  = (ushort*)(ws + 16384);     // 24576 bf16
    ushort* tB16 = (ushort*)(ws + 32768);     // NV*64 bf16
    ushort* pB16 = tB16 + (size_t)NV * 64;
    ushort* gB16 = pB16 + (size_t)NV * 64;
    float* yB    = ws + 32768 + (3 * (size_t)NV * 64) / 2;  // NV*64 fp32
    float* fbase = yB + (size_t)NV * 64;      // 3*NV*48 fp32
    float* fD = fbase;
    float* fH = fbase + (size_t)NV * 48;
    float* fW = fbase + (size_t)NV * 48 * 2;
    float* crossB = fbase;                    // reuse (f dead after ysum)
    float* out = (float*)d_out;

    k_prep<<<1, 256, 0, stream>>>(thw, phw, gww, rw, wTb, rWT);

    const float* hin = x;
    for (int layer = 0; layer < 2; ++layer) {
        k_proj<<<NV / 64, 256, 0, stream>>>(hin, wTb, thb, phb, gwb, tB16, pB16, gB16);
        k_scores<<<3456, 256, 0, stream>>>(tB16, pB16, fbase);
        k_softmax<<<NV / 4, 256, 0, stream>>>(fD, fH, fW);
        for (int ax = 0; ax < 3; ++ax)
            k_ysum<<<2304, 128, 0, stream>>>((ax == 0 ? fD : ax == 1 ? fH : fW),
                gB16, yB, ax, ax > 0);
        k_cross<<<NV / 64, 256, 0, stream>>>(yB, rWT, rb, crossB);
        k_gnpart<<<1024, 256, 0, stream>>>(crossB, part);
        k_gnfin<<<1, 64, 0, stream>>>(part, stats);
        k_gnapply<<<(int)(((long)2 * Cc * SP / 4) / 256), 256, 0, stream>>>(
            hin, crossB, stats, gnw + layer * 128, gnb + layer * 128, out);
        hin = out;
    }
    k_bnpart<<<1024, 256, 0, stream>>>(out, part);
    k_bnfin<<<1, 128, 0, stream>>>(part, bnw, bnb, bnss);
    k_bnrelu<<<(int)(((long)2 * Cc * SP / 4) / 256), 256, 0, stream>>>(out, bnss, out);
}